// Round 1
// baseline (317.369 us; speedup 1.0000x reference)
//
#include <hip/hip_runtime.h>

// DayAdapter: out[b,t,e] = softsign( sum_d x[b,t,d] * W[day[b],d,e] + bias[day[b],e] )
// x: [64,1024,512] f32, day_ids: [64] i32, W: [24,512,512] f32, b: [24,512] f32
// bf16 MFMA (16x16x32), fp32 accumulate. 128x128 block tile, BK=32, 256 threads.

#define DIM 512
#define SEQ 1024
#define BM 128
#define BN 128
#define BK 32
#define LDK 40  // BK + 8 pad (keeps ds_read_b128 16B-aligned, breaks bank-conflict stride)

typedef __bf16 bf16x8 __attribute__((ext_vector_type(8)));
typedef __bf16 bf16x4 __attribute__((ext_vector_type(4)));
typedef float  f32x4  __attribute__((ext_vector_type(4)));

__global__ __launch_bounds__(256, 2)
void day_adapter_kernel(const float* __restrict__ x,
                        const int*   __restrict__ day_ids,
                        const float* __restrict__ W,
                        const float* __restrict__ bias,
                        float*       __restrict__ out)
{
    __shared__ __align__(16) __bf16 As[BM][LDK];  // A tile: [m][k]
    __shared__ __align__(16) __bf16 Bs[BN][LDK];  // B tile transposed: [n][k]

    const int tid = threadIdx.x;
    const int bb  = blockIdx.z;          // batch
    const int m0  = blockIdx.y * BM;     // row tile base (0..896)
    const int n0  = blockIdx.x * BN;     // col tile base (0..384)
    const int day = day_ids[bb];         // block-uniform scalar load

    const float* xb = x   + (size_t)bb  * SEQ * DIM + (size_t)m0 * DIM;
    const float* Wb = W   + (size_t)day * DIM * DIM + n0;
    float*       ob = out + (size_t)bb  * SEQ * DIM + (size_t)m0 * DIM + n0;

    // A staging: 128 rows x 32 cols; thread -> (row = tid>>3 (+t*32), col4 = (tid&7)*4)
    const int a_row = tid >> 3;          // 0..31
    const int a_col = (tid & 7) * 4;     // 0,4,...,28
    // B staging: 32 k-rows x 128 n-cols; thread -> (k = tid&31, n16 = (tid>>5)*16)
    const int b_k = tid & 31;
    const int b_n = (tid >> 5) * 16;

    const int wave = tid >> 6;           // 0..3
    const int lane = tid & 63;
    const int wm   = (wave >> 1) * 64;   // wave row offset
    const int wn   = (wave & 1) * 64;    // wave col offset
    const int l15  = lane & 15;
    const int kq   = (lane >> 4) * 8;    // k quad offset for A/B fragments

    f32x4 acc[4][4];
    const f32x4 zero = {0.f, 0.f, 0.f, 0.f};
    #pragma unroll
    for (int i = 0; i < 4; ++i)
        #pragma unroll
        for (int j = 0; j < 4; ++j)
            acc[i][j] = zero;

    for (int kk = 0; kk < DIM; kk += BK) {
        // ---- stage A (f32 -> bf16), coalesced float4 loads, 8B LDS writes ----
        #pragma unroll
        for (int t = 0; t < 4; ++t) {
            const int r = a_row + t * 32;
            const float4 f = *(const float4*)(xb + (size_t)r * DIM + kk + a_col);
            bf16x4 v;
            v[0] = (__bf16)f.x; v[1] = (__bf16)f.y;
            v[2] = (__bf16)f.z; v[3] = (__bf16)f.w;
            *(bf16x4*)&As[r][a_col] = v;
        }
        // ---- stage B transposed (f32 -> bf16): load 16 floats along n, scatter u16 ----
        {
            const float* src = Wb + (size_t)(kk + b_k) * DIM + b_n;
            const float4 g0 = ((const float4*)src)[0];
            const float4 g1 = ((const float4*)src)[1];
            const float4 g2 = ((const float4*)src)[2];
            const float4 g3 = ((const float4*)src)[3];
            const float v[16] = {g0.x,g0.y,g0.z,g0.w, g1.x,g1.y,g1.z,g1.w,
                                 g2.x,g2.y,g2.z,g2.w, g3.x,g3.y,g3.z,g3.w};
            #pragma unroll
            for (int i = 0; i < 16; ++i)
                Bs[b_n + i][b_k] = (__bf16)v[i];
        }
        __syncthreads();

        // ---- fragments: ds_read_b128, k-contiguous ----
        bf16x8 af[4], bfr[4];
        #pragma unroll
        for (int t = 0; t < 4; ++t)
            af[t] = *(const bf16x8*)&As[wm + t * 16 + l15][kq];
        #pragma unroll
        for (int t = 0; t < 4; ++t)
            bfr[t] = *(const bf16x8*)&Bs[wn + t * 16 + l15][kq];

        #pragma unroll
        for (int i = 0; i < 4; ++i)
            #pragma unroll
            for (int j = 0; j < 4; ++j)
                acc[i][j] = __builtin_amdgcn_mfma_f32_16x16x32_bf16(
                    af[i], bfr[j], acc[i][j], 0, 0, 0);

        __syncthreads();
    }

    // ---- epilogue: bias + softsign, fp32 stores ----
    float bv[4];
    #pragma unroll
    for (int j = 0; j < 4; ++j)
        bv[j] = bias[(size_t)day * DIM + n0 + wn + j * 16 + l15];

    #pragma unroll
    for (int i = 0; i < 4; ++i) {
        const int rbase = wm + i * 16 + (lane >> 4) * 4;  // C/D: row = quad*4 + reg
        #pragma unroll
        for (int j = 0; j < 4; ++j) {
            const int col = wn + j * 16 + l15;            // C/D: col = lane&15
            #pragma unroll
            for (int r = 0; r < 4; ++r) {
                const float y = acc[i][j][r] + bv[j];
                ob[(size_t)(rbase + r) * DIM + col] = y / (1.0f + fabsf(y));
            }
        }
    }
}

extern "C" void kernel_launch(void* const* d_in, const int* in_sizes, int n_in,
                              void* d_out, int out_size, void* d_ws, size_t ws_size,
                              hipStream_t stream) {
    const float* x        = (const float*)d_in[0];
    const int*   day_ids  = (const int*)  d_in[1];
    const float* W        = (const float*)d_in[2];
    const float* bias     = (const float*)d_in[3];
    float*       out      = (float*)d_out;

    dim3 grid(DIM / BN, SEQ / BM, 64);   // (4, 8, 64) = 2048 blocks
    day_adapter_kernel<<<grid, 256, 0, stream>>>(x, day_ids, W, bias, out);
}

// Round 2
// 279.247 us; speedup vs baseline: 1.1365x; 1.1365x over previous
//
#include <hip/hip_runtime.h>

// DayAdapter: out[b,t,e] = softsign( x[b,t,:] @ W[day[b]] + bias[day[b]] )
// x: [64,1024,512] f32, day_ids: [64] i32, W: [24,512,512] f32, bias: [24,512] f32
//
// Round 2: (a) pre-pass converts W -> Wt[day][n][k] bf16 in d_ws, so main-loop B
// staging is pure global_load_lds dwordx4 (no cvt, no transpose scatter);
// (b) BK=64 (32 MFMA between barriers); (c) XOR-swizzled B chunk layout for
// conflict-free frag reads under the lane-linear LDS layout global_load_lds forces;
// (d) XCD swizzle: the 4 N-tiles sharing an x row-tile get block ids = same mod 8.

#define DIM 512
#define SEQ 1024
#define NB 64
#define NDAYS 24
#define BM 128
#define BN 128
#define BK 64
#define LDA (BK + 8)   // A row stride (bf16): +8 pad -> frag reads 2-way (free)

typedef __bf16 bf16x8 __attribute__((ext_vector_type(8)));
typedef __bf16 bf16x4 __attribute__((ext_vector_type(4)));
typedef float  f32x4  __attribute__((ext_vector_type(4)));

__device__ __forceinline__ void gll16(const void* g, void* l) {
    __builtin_amdgcn_global_load_lds(
        (const __attribute__((address_space(1))) unsigned int*)g,
        (__attribute__((address_space(3))) unsigned int*)l,
        16, 0, 0);
}

// ---- kernel 1: Wt[d][n][k] = bf16(W[d][k][n]) ----
__global__ __launch_bounds__(256)
void transpose_w_kernel(const float* __restrict__ W, __bf16* __restrict__ Wt) {
    __shared__ __bf16 T[32][33];
    const int d  = blockIdx.z;
    const int k0 = blockIdx.x * 32;
    const int n0 = blockIdx.y * 32;
    const int tx = threadIdx.x & 31;
    const int ty = threadIdx.x >> 5;   // 0..7
    const float* Wd = W + (size_t)d * DIM * DIM;
    #pragma unroll
    for (int i = 0; i < 4; ++i) {
        const int k = ty + i * 8;
        T[tx][k] = (__bf16)Wd[(size_t)(k0 + k) * DIM + n0 + tx];  // coalesced f32 read
    }
    __syncthreads();
    __bf16* Wtd = Wt + (size_t)d * DIM * DIM;
    #pragma unroll
    for (int i = 0; i < 4; ++i) {
        const int n = ty + i * 8;
        Wtd[(size_t)(n0 + n) * DIM + k0 + tx] = T[n][tx];         // coalesced bf16 write
    }
}

// ---- kernel 2: main GEMM + bias + softsign ----
__global__ __launch_bounds__(256, 4)
void day_adapter_kernel(const float* __restrict__ x,
                        const int*   __restrict__ day_ids,
                        const __bf16* __restrict__ Wt,
                        const float* __restrict__ bias,
                        float*       __restrict__ out)
{
    __shared__ __align__(16) __bf16 As[BM][LDA];    // 128 x 72 bf16 = 18432 B
    __shared__ __align__(16) __bf16 Bs[BN * BK];    // 16384 B, swizzled 16B chunks

    // XCD swizzle: L = xcdslot(3b) | ntile(2b) | hi(6b); the 4 ntiles of one
    // (m,b) share L mod 8 -> same XCD under round-robin dispatch.
    const int L  = blockIdx.x;
    const int g  = (L >> 3) & 3;
    const int mb = (L & 7) | ((L >> 5) << 3);   // 0..511
    const int m  = mb & 7;
    const int bb = mb >> 3;

    const int n0  = g * BN;
    const int m0  = m * BM;
    const int tid = threadIdx.x;
    const int day = day_ids[bb];

    const float*  xb  = x   + (size_t)bb  * SEQ * DIM + (size_t)m0 * DIM;
    const __bf16* Wtb = Wt  + (size_t)day * DIM * DIM + (size_t)n0 * DIM;
    float*        ob  = out + (size_t)bb  * SEQ * DIM + (size_t)m0 * DIM + n0;

    const int wave = tid >> 6;
    const int lane = tid & 63;
    const int wm   = (wave >> 1) * 64;
    const int wn   = (wave & 1) * 64;
    const int l15  = lane & 15;
    const int quad = lane >> 4;          // 0..3
    const int kq   = quad * 8;

    // A staging map: 2 halves x 4 float4s; row = tid>>2 (+64), col = (tid&3)*4 + i*16
    const int a_row = tid >> 2;          // 0..63
    const int a_col = (tid & 3) * 4;

    // B staging: slot s = p*256 + tid; n = s>>3, c' = s&7, c = c' ^ (n&7)
    // LDS base must be wave-uniform: (p*256 + (tid & ~63)) * 16, lane*16 implicit.
    char* BsB = (char*)Bs;

    f32x4 acc[4][4];
    const f32x4 zero = {0.f, 0.f, 0.f, 0.f};
    #pragma unroll
    for (int i = 0; i < 4; ++i)
        #pragma unroll
        for (int j = 0; j < 4; ++j) acc[i][j] = zero;

    for (int kk = 0; kk < DIM; kk += BK) {
        // -- B: async global->LDS, 4 x 16B per thread, swizzled chunk placement --
        #pragma unroll
        for (int p = 0; p < 4; ++p) {
            const int s  = p * 256 + tid;
            const int n  = s >> 3;
            const int cp = s & 7;
            const int c  = cp ^ (n & 7);
            gll16(Wtb + (size_t)n * DIM + kk + c * 8,
                  BsB + (size_t)(p * 256 + (tid & ~63)) * 16);
        }
        // -- A: f32 loads -> bf16 cvt -> 8B LDS writes --
        #pragma unroll
        for (int h = 0; h < 2; ++h) {
            const int r = a_row + h * 64;
            #pragma unroll
            for (int i = 0; i < 4; ++i) {
                const int col = a_col + i * 16;
                const float4 f = *(const float4*)(xb + (size_t)r * DIM + kk + col);
                bf16x4 v;
                v[0] = (__bf16)f.x; v[1] = (__bf16)f.y;
                v[2] = (__bf16)f.z; v[3] = (__bf16)f.w;
                *(bf16x4*)&As[r][col] = v;
            }
        }
        __syncthreads();

        #pragma unroll
        for (int ks = 0; ks < 2; ++ks) {
            bf16x8 af[4], bfr[4];
            #pragma unroll
            for (int i = 0; i < 4; ++i)
                af[i] = *(const bf16x8*)&As[wm + i * 16 + l15][ks * 32 + kq];
            #pragma unroll
            for (int j = 0; j < 4; ++j) {
                const int n  = wn + j * 16 + l15;
                const int c  = ks * 4 + quad;
                const int cp = c ^ (n & 7);
                bfr[j] = *(const bf16x8*)&Bs[n * BK + cp * 8];
            }
            #pragma unroll
            for (int i = 0; i < 4; ++i)
                #pragma unroll
                for (int j = 0; j < 4; ++j)
                    acc[i][j] = __builtin_amdgcn_mfma_f32_16x16x32_bf16(
                        af[i], bfr[j], acc[i][j], 0, 0, 0);
        }
        __syncthreads();
    }

    // -- epilogue: bias + softsign --
    float bv[4];
    #pragma unroll
    for (int j = 0; j < 4; ++j)
        bv[j] = bias[(size_t)day * DIM + n0 + wn + j * 16 + l15];

    #pragma unroll
    for (int i = 0; i < 4; ++i) {
        const int rbase = wm + i * 16 + quad * 4;        // C/D: row = quad*4 + reg
        #pragma unroll
        for (int j = 0; j < 4; ++j) {
            const int col = wn + j * 16 + l15;           // C/D: col = lane&15
            #pragma unroll
            for (int r = 0; r < 4; ++r) {
                const float y = acc[i][j][r] + bv[j];
                ob[(size_t)(rbase + r) * DIM + col] = y / (1.0f + fabsf(y));
            }
        }
    }
}

extern "C" void kernel_launch(void* const* d_in, const int* in_sizes, int n_in,
                              void* d_out, int out_size, void* d_ws, size_t ws_size,
                              hipStream_t stream) {
    const float* x       = (const float*)d_in[0];
    const int*   day_ids = (const int*)  d_in[1];
    const float* W       = (const float*)d_in[2];
    const float* bias    = (const float*)d_in[3];
    float*       out     = (float*)d_out;
    __bf16*      Wt      = (__bf16*)d_ws;   // 24*512*512*2 = 12.58 MB

    dim3 tgrid(DIM / 32, DIM / 32, NDAYS);  // (16,16,24)
    transpose_w_kernel<<<tgrid, 256, 0, stream>>>(W, Wt);

    day_adapter_kernel<<<dim3(2048), 256, 0, stream>>>(x, day_ids, Wt, bias, out);
}